// Round 1
// baseline (93.348 us; speedup 1.0000x reference)
//
#include <hip/hip_runtime.h>

#define BATCH   16
#define CLEN    2048
#define DHEAD   2048
#define NT      256
#define ROWS    8      // rows (c values) per block in main kernel

// ws layout (floats):
// [0..5]              : M00,M01,M10,M11,b2_0,b2_1
// [8 .. 8+2047]       : u0
// [2056 .. 4103]      : u1
// [4104 .. 6151]      : w  (= bv@Wo + bo)
// [6152 .. ]          : partials [32 chunks][3][2048]
#define WS_U0   8
#define WS_U1   (8 + DHEAD)
#define WS_W    (8 + 2*DHEAD)
#define WS_PART (8 + 3*DHEAD)

// ---------------- prep A: M = Wq Wk^T (2x2), b2 = Wk @ bq (2) ----------------
__global__ void prep_small(const float* __restrict__ Wq, const float* __restrict__ Wk,
                           const float* __restrict__ bq, float* __restrict__ ws) {
    __shared__ float red[NT][6];
    int t = threadIdx.x;
    float m00=0.f,m01=0.f,m10=0.f,m11=0.f,b20=0.f,b21=0.f;
    for (int d = t; d < DHEAD; d += NT) {
        float q0 = Wq[d], q1 = Wq[DHEAD + d];
        float k0 = Wk[d], k1 = Wk[DHEAD + d];
        float bb = bq[d];
        m00 += q0*k0; m01 += q0*k1; m10 += q1*k0; m11 += q1*k1;
        b20 += k0*bb; b21 += k1*bb;
    }
    red[t][0]=m00; red[t][1]=m01; red[t][2]=m10;
    red[t][3]=m11; red[t][4]=b20; red[t][5]=b21;
    __syncthreads();
    for (int s = NT/2; s > 0; s >>= 1) {
        if (t < s) {
            #pragma unroll
            for (int j = 0; j < 6; ++j) red[t][j] += red[t+s][j];
        }
        __syncthreads();
    }
    if (t < 6) ws[t] = red[0][t];
}

// ---------------- prep B1: partial u0,u1,w over h-chunks of 64 ----------------
__global__ void prep_u_partial(const float* __restrict__ Wv, const float* __restrict__ bv,
                               const float* __restrict__ Wo, float* __restrict__ ws) {
    int o  = blockIdx.x * NT + threadIdx.x;      // column of Wo, 0..2047
    int hb = blockIdx.y * 64;                    // 32 chunks of 64 rows
    float p0=0.f, p1=0.f, pw=0.f;
    #pragma unroll 4
    for (int h = hb; h < hb + 64; ++h) {
        float wo = Wo[(size_t)h * DHEAD + o];
        p0 += Wv[h]         * wo;
        p1 += Wv[DHEAD + h] * wo;
        pw += bv[h]         * wo;
    }
    float* part = ws + WS_PART;
    part[((size_t)blockIdx.y*3 + 0)*DHEAD + o] = p0;
    part[((size_t)blockIdx.y*3 + 1)*DHEAD + o] = p1;
    part[((size_t)blockIdx.y*3 + 2)*DHEAD + o] = pw;
}

// ---------------- prep B2: reduce partials, add bo ----------------
__global__ void prep_u_final(const float* __restrict__ bo, float* __restrict__ ws) {
    int o = blockIdx.x * NT + threadIdx.x;
    const float* part = ws + WS_PART;
    float u0=0.f, u1=0.f, w=0.f;
    #pragma unroll
    for (int y = 0; y < 32; ++y) {
        u0 += part[((size_t)y*3 + 0)*DHEAD + o];
        u1 += part[((size_t)y*3 + 1)*DHEAD + o];
        w  += part[((size_t)y*3 + 2)*DHEAD + o];
    }
    ws[WS_U0 + o] = u0;
    ws[WS_U1 + o] = u1;
    ws[WS_W  + o] = w + bo[o];
}

// ---------------- main: causal softmax on scalar logits + rank-2 output ----------------
__device__ __forceinline__ float waveMax(float v) {
    #pragma unroll
    for (int off = 32; off > 0; off >>= 1) v = fmaxf(v, __shfl_xor(v, off));
    return v;
}
__device__ __forceinline__ float waveSum(float v) {
    #pragma unroll
    for (int off = 32; off > 0; off >>= 1) v += __shfl_xor(v, off);
    return v;
}

__launch_bounds__(NT, 2)
__global__ void attn_out(const float* __restrict__ x, const float* __restrict__ ws,
                         float* __restrict__ out) {
    __shared__ float uu0[DHEAD], uu1[DHEAD], uwv[DHEAD];
    __shared__ float smax[4];
    __shared__ float ssum[4][3];

    const int t     = threadIdx.x;
    const int b     = blockIdx.y;
    const int ctile = blockIdx.x;
    const int lane  = t & 63;
    const int wave  = t >> 6;

    // stage u0,u1,w in LDS (read-broadcast later by all rows)
    for (int i = t; i < DHEAD; i += NT) {
        uu0[i] = ws[WS_U0 + i];
        uu1[i] = ws[WS_U1 + i];
        uwv[i] = ws[WS_W  + i];
    }
    const float M00 = ws[0], M01 = ws[1], M10 = ws[2], M11 = ws[3];
    const float B20 = ws[4], B21 = ws[5];
    const float* xb = x + (size_t)b * CLEN * 2;
    __syncthreads();

    for (int r = 0; r < ROWS; ++r) {
        const int c = ctile * ROWS + r;
        const int n = c + 1;                       // causal row length
        const float xc0 = xb[2*c], xc1 = xb[2*c + 1];
        const float g0 = M00*xc0 + M10*xc1 + B20;  // (M^T x_c + b2)
        const float g1 = M01*xc0 + M11*xc1 + B21;

        float le[8], xe0[8], xe1[8];
        float lmax = -1e30f;
        #pragma unroll
        for (int k = 0; k < 8; ++k) {
            int e = t + k * NT;
            bool ok = e < n;
            float2 xe = ok ? *reinterpret_cast<const float2*>(xb + 2*e)
                           : make_float2(0.f, 0.f);
            xe0[k] = xe.x; xe1[k] = xe.y;
            float l = ok ? (g0*xe.x + g1*xe.y) : -1e30f;
            le[k] = l;
            lmax = fmaxf(lmax, l);
        }
        // block-reduce max
        float wm = waveMax(lmax);
        if (lane == 0) smax[wave] = wm;
        __syncthreads();
        const float m = fmaxf(fmaxf(smax[0], smax[1]), fmaxf(smax[2], smax[3]));

        // exp + weighted sums (registers only, no re-load)
        float ps = 0.f, p0 = 0.f, p1 = 0.f;
        #pragma unroll
        for (int k = 0; k < 8; ++k) {
            int e = t + k * NT;
            if (e < n) {
                float p = __expf(le[k] - m);
                ps += p; p0 += p * xe0[k]; p1 += p * xe1[k];
            }
        }
        float rs = waveSum(ps), r0 = waveSum(p0), r1 = waveSum(p1);
        __syncthreads();                 // smax reads done; ssum from prev row done
        if (lane == 0) { ssum[wave][0] = rs; ssum[wave][1] = r0; ssum[wave][2] = r1; }
        __syncthreads();
        const float tot = ssum[0][0] + ssum[1][0] + ssum[2][0] + ssum[3][0];
        const float t0  = ssum[0][1] + ssum[1][1] + ssum[2][1] + ssum[3][1];
        const float t1  = ssum[0][2] + ssum[1][2] + ssum[2][2] + ssum[3][2];
        const float inv = 1.0f / tot;
        const float S0 = t0 * inv, S1 = t1 * inv;

        // epilogue: out[b,c,:] = S0*u0 + S1*u1 + w   (float4 stores)
        float* orow = out + ((size_t)(b * CLEN + c)) * DHEAD;
        #pragma unroll
        for (int k = 0; k < 2; ++k) {
            int i4 = t + k * NT;            // float4 index, 512 per row
            float4 a0 = *reinterpret_cast<const float4*>(&uu0[i4*4]);
            float4 a1 = *reinterpret_cast<const float4*>(&uu1[i4*4]);
            float4 aw = *reinterpret_cast<const float4*>(&uwv[i4*4]);
            float4 res;
            res.x = S0*a0.x + S1*a1.x + aw.x;
            res.y = S0*a0.y + S1*a1.y + aw.y;
            res.z = S0*a0.z + S1*a1.z + aw.z;
            res.w = S0*a0.w + S1*a1.w + aw.w;
            *reinterpret_cast<float4*>(&orow[i4*4]) = res;
        }
        __syncthreads();                 // protect ssum/smax for next row
    }
}

extern "C" void kernel_launch(void* const* d_in, const int* in_sizes, int n_in,
                              void* d_out, int out_size, void* d_ws, size_t ws_size,
                              hipStream_t stream) {
    const float* x  = (const float*)d_in[0];
    const float* Wk = (const float*)d_in[1];
    const float* bk = (const float*)d_in[2];  (void)bk; // cancels in softmax
    const float* Wq = (const float*)d_in[3];
    const float* bq = (const float*)d_in[4];
    const float* Wv = (const float*)d_in[5];
    const float* bv = (const float*)d_in[6];
    const float* Wo = (const float*)d_in[7];
    const float* bo = (const float*)d_in[8];
    float* out = (float*)d_out;
    float* ws  = (float*)d_ws;

    prep_small<<<1, NT, 0, stream>>>(Wq, Wk, bq, ws);
    prep_u_partial<<<dim3(DHEAD / NT, 32), NT, 0, stream>>>(Wv, bv, Wo, ws);
    prep_u_final<<<DHEAD / NT, NT, 0, stream>>>(bo, ws);
    attn_out<<<dim3(CLEN / ROWS, BATCH), NT, 0, stream>>>(x, ws, out);
}